// Round 2
// baseline (990.368 us; speedup 1.0000x reference)
//
#include <hip/hip_runtime.h>
#include <hip/hip_bf16.h>
#include <stdint.h>

#define N_NODES 30000
#define N_PAD   30080   // 235 * 128
#define N_EDGES 100000
#define DIM     512

typedef unsigned short ushort_t;
typedef __attribute__((ext_vector_type(8))) short short8;
typedef __attribute__((ext_vector_type(4))) float floatx4;

__device__ __forceinline__ float b2f(ushort_t b) { return __uint_as_float(((unsigned)b) << 16); }
__device__ __forceinline__ ushort_t f2b(float f) {
    unsigned u = __float_as_uint(f);
    u += 0x7FFFu + ((u >> 16) & 1u);   // round-nearest-even
    return (ushort_t)(u >> 16);
}

// ---------------- pad/convert h (f32) into padded bf16 buffers ----------------
__global__ __launch_bounds__(256) void pad_copy2(const float* __restrict__ h0,
                                                 const float* __restrict__ h1,
                                                 ushort_t* __restrict__ d0,
                                                 ushort_t* __restrict__ d1) {
    const int total = N_PAD * DIM / 4;
    const int valid = N_NODES * DIM / 4;
    int idx = blockIdx.x * 256 + threadIdx.x;
    if (idx >= total) return;
    const float* s = blockIdx.y ? h1 : h0;
    ushort_t* d = blockIdx.y ? d1 : d0;
    float4 v = make_float4(0.f, 0.f, 0.f, 0.f);
    if (idx < valid) v = ((const float4*)s)[idx];
    ushort_t o[4] = {f2b(v.x), f2b(v.y), f2b(v.z), f2b(v.w)};
    ((uint2*)d)[idx] = *(const uint2*)o;
}

// ---------------- fold per-head relation matrix into weight, produce W^T (bf16) ----------------
// WfT[n=h*64+d][i] = sum_c W[i][h*64+c] * A[h][c][d];  bf[n] = sum_c b[h*64+c]*A[h][c][d]
__global__ __launch_bounds__(256) void fuse_weights(const float* __restrict__ W,
                                                    const float* __restrict__ bvec,
                                                    const float* __restrict__ A,
                                                    ushort_t* __restrict__ WfT,
                                                    float* __restrict__ bf) {
    int idx = blockIdx.x * 256 + threadIdx.x;  // 512*512
    int n = idx & 511;
    int i = idx >> 9;
    int h = n >> 6, d = n & 63;
    const float* wrow = W + i * DIM + h * 64;
    const float* acol = A + h * 4096 + d;
    float s = 0.f;
#pragma unroll 8
    for (int c = 0; c < 64; ++c) s += wrow[c] * acol[c * 64];
    WfT[n * DIM + i] = f2b(s);
    if (i == 0) {
        const float* bh = bvec + h * 64;
        float sb = 0.f;
        for (int c = 0; c < 64; ++c) sb += bh[c] * acol[c * 64];
        bf[n] = sb;
    }
}

// ---------------- 4x 512x512 transpose f32 -> bf16 (for Wq0,Wq1,Wa0,Wa1) ----------------
__global__ __launch_bounds__(256) void transpose4(const float* w0, const float* w1,
                                                  const float* w2, const float* w3,
                                                  ushort_t* o0, ushort_t* o1,
                                                  ushort_t* o2, ushort_t* o3) {
    const float* W; ushort_t* O;
    switch (blockIdx.y) {
        case 0: W = w0; O = o0; break;
        case 1: W = w1; O = o1; break;
        case 2: W = w2; O = o2; break;
        default: W = w3; O = o3; break;
    }
    __shared__ float tile[32][33];
    int bx = blockIdx.x & 15, by = blockIdx.x >> 4;
    int tx = threadIdx.x & 31, ty = threadIdx.x >> 5;  // 32x8
#pragma unroll
    for (int r = 0; r < 32; r += 8) tile[ty + r][tx] = W[(by * 32 + ty + r) * DIM + bx * 32 + tx];
    __syncthreads();
#pragma unroll
    for (int r = 0; r < 32; r += 8) O[(bx * 32 + ty + r) * DIM + by * 32 + tx] = f2b(tile[tx][ty + r]);
}

// ---------------- CSR build ----------------
__global__ __launch_bounds__(256) void hist_kernel(const int* __restrict__ dstE, int* __restrict__ cnt) {
    int e = blockIdx.x * 256 + threadIdx.x;
    if (e < N_EDGES) atomicAdd(&cnt[dstE[e]], 1);
}

__global__ __launch_bounds__(1024) void scan_excl(const int* __restrict__ cnt, int* __restrict__ row_ptr) {
    __shared__ int sums[1024];
    int tid = threadIdx.x;
    int base = tid * 32;
    int loc[32];
    int s = 0;
#pragma unroll
    for (int i = 0; i < 32; ++i) {
        int idx = base + i;
        int v = (idx < N_NODES) ? cnt[idx] : 0;
        s += v;
        loc[i] = s;  // inclusive within chunk
    }
    sums[tid] = s;
    __syncthreads();
    for (int off = 1; off < 1024; off <<= 1) {
        int add = (tid >= off) ? sums[tid - off] : 0;
        __syncthreads();
        sums[tid] += add;
        __syncthreads();
    }
    int pre = (tid > 0) ? sums[tid - 1] : 0;
    if (tid == 0) row_ptr[0] = 0;
#pragma unroll
    for (int i = 0; i < 32; ++i) {
        int idx = base + i;
        if (idx < N_NODES) row_ptr[idx + 1] = pre + loc[i];
    }
}

__global__ __launch_bounds__(256) void scatter_kernel(const int* __restrict__ srcE,
                                                      const int* __restrict__ dstE,
                                                      const int* __restrict__ row_ptr,
                                                      int* __restrict__ fill,
                                                      int* __restrict__ colarr) {
    int e = blockIdx.x * 256 + threadIdx.x;
    if (e >= N_EDGES) return;
    int d = dstE[e];
    int pos = atomicAdd(&fill[d], 1);
    colarr[row_ptr[d] + pos] = srcE[e];
}

// ---------------- MFMA GEMM: C[M,512] = A[M,512] @ BT[512,512]^T + bias ----------------
// MODE 1: final f32 out with sigmoid-skip blend vs f32 residual + row guard. MODE 2: bf16 out.
typedef const __attribute__((address_space(1))) unsigned int gu32;
typedef __attribute__((address_space(3))) unsigned int lu32;
__device__ __forceinline__ void gload_lds16(const void* g, void* l) {
    __builtin_amdgcn_global_load_lds((gu32*)g, (lu32*)l, 16, 0, 0);
}

template <int MODE>
__global__ __launch_bounds__(256) void gemm512(const ushort_t* __restrict__ A,
                                               const ushort_t* __restrict__ BT,
                                               const float* __restrict__ bias,
                                               float* __restrict__ Cf,
                                               ushort_t* __restrict__ Cb,
                                               const float* __restrict__ Hres,
                                               const float* __restrict__ skipv, int rel) {
    __shared__ alignas(16) ushort_t As[128 * 32];
    __shared__ alignas(16) ushort_t Bs[128 * 32];
    int tn = blockIdx.x & 3;
    int tm = blockIdx.x >> 2;
    int m0 = tm * 128, n0 = tn * 128;
    int tid = threadIdx.x;
    int w = tid >> 6, l = tid & 63;
    int wr = w >> 1, wc = w & 1;
    int fr = l & 15, fq = l >> 4;

    floatx4 acc[4][4] = {};

    const ushort_t* aF = &As[(wr * 64 + fr) * 32 + fq * 8];
    const ushort_t* bF = &Bs[(wc * 64 + fr) * 32 + fq * 8];

    int row0 = tid >> 2, c0 = (tid & 3) * 8;          // staging slot it=0
    int row1 = (tid + 256) >> 2, c1 = (tid & 3) * 8;  // it=1
    int lb0 = (w * 64) * 16;
    int lb1 = (256 + w * 64) * 16;

#pragma unroll 1
    for (int kt = 0; kt < 16; ++kt) {
        int k0 = kt * 32;
        if (kt) __syncthreads();
        gload_lds16(A + (size_t)(m0 + row0) * DIM + k0 + c0, (char*)As + lb0);
        gload_lds16(BT + (size_t)(n0 + row0) * DIM + k0 + c0, (char*)Bs + lb0);
        gload_lds16(A + (size_t)(m0 + row1) * DIM + k0 + c1, (char*)As + lb1);
        gload_lds16(BT + (size_t)(n0 + row1) * DIM + k0 + c1, (char*)Bs + lb1);
        __syncthreads();

        short8 af[4], bf[4];
#pragma unroll
        for (int i = 0; i < 4; ++i) af[i] = *(const short8*)(aF + i * 16 * 32);
#pragma unroll
        for (int j = 0; j < 4; ++j) bf[j] = *(const short8*)(bF + j * 16 * 32);
#pragma unroll
        for (int i = 0; i < 4; ++i)
#pragma unroll
            for (int j = 0; j < 4; ++j)
                acc[i][j] = __builtin_amdgcn_mfma_f32_16x16x32_bf16(af[i], bf[j], acc[i][j], 0, 0, 0);
    }

    float alpha = 1.f, onem = 0.f;
    if (MODE == 1) {
        float sk = skipv[rel];
        alpha = 1.f / (1.f + __expf(-sk));
        onem = 1.f - alpha;
    }
#pragma unroll
    for (int i = 0; i < 4; ++i) {
#pragma unroll
        for (int j = 0; j < 4; ++j) {
            int col = n0 + wc * 64 + j * 16 + fr;
            float bc = bias[col];
#pragma unroll
            for (int r = 0; r < 4; ++r) {
                int grow = m0 + wr * 64 + i * 16 + fq * 4 + r;
                float v = acc[i][j][r] + bc;
                if (MODE == 2) {
                    Cb[(size_t)grow * DIM + col] = f2b(v);
                } else {
                    if (grow < N_NODES) {
                        float hr = Hres[(size_t)grow * DIM + col];
                        Cf[(size_t)grow * DIM + col] = v * alpha + hr * onem;
                    }
                }
            }
        }
    }
}

// ---------------- per-(node,head) online-softmax aggregation ----------------
__global__ __launch_bounds__(256) void node_attn(const ushort_t* __restrict__ q,
                                                 const ushort_t* __restrict__ kA,
                                                 const ushort_t* __restrict__ vM,
                                                 const int* __restrict__ row_ptr,
                                                 const int* __restrict__ colarr,
                                                 const float* __restrict__ pri,
                                                 ushort_t* __restrict__ t) {
    int w = threadIdx.x >> 6, l = threadIdx.x & 63;
    int task = blockIdx.x * 4 + w;  // < N_PAD*8
    int n = task >> 3, h = task & 7;
    int base = n * DIM + h * 64 + l;
    float qd = b2f(q[base]);
    int lo = 0, hi = 0;
    if (n < N_NODES) { lo = row_ptr[n]; hi = row_ptr[n + 1]; }
    float prih = pri[h] * 0.125f;  // pri / sqrt(64)
    float m = -3.0e38f, s = 0.f, acc = 0.f;
    for (int j = lo; j < hi; ++j) {
        int sn = colarr[j];
        float kv = b2f(kA[(size_t)sn * DIM + h * 64 + l]);
        float dot = qd * kv;
#pragma unroll
        for (int off = 32; off > 0; off >>= 1) dot += __shfl_xor(dot, off, 64);
        float att = dot * prih;
        float mn = fmaxf(m, att);
        float e0 = __expf(m - mn);
        float e1 = __expf(att - mn);
        float vv = b2f(vM[(size_t)sn * DIM + h * 64 + l]);
        acc = acc * e0 + e1 * vv;
        s = s * e0 + e1;
        m = mn;
    }
    t[base] = f2b((hi > lo) ? acc / s : 0.f);
}

// ---------------- host launch ----------------
extern "C" void kernel_launch(void* const* d_in, const int* in_sizes, int n_in,
                              void* d_out, int out_size, void* d_ws, size_t ws_size,
                              hipStream_t stream) {
    (void)in_sizes; (void)n_in; (void)out_size; (void)ws_size;
    const float* h_paper  = (const float*)d_in[0];
    const float* h_author = (const float*)d_in[1];
    const int* src0 = (const int*)d_in[2];
    const int* dst0 = (const int*)d_in[3];
    const int* src1 = (const int*)d_in[4];
    const int* dst1 = (const int*)d_in[5];
    const float* Wk0 = (const float*)d_in[6];  const float* bk0 = (const float*)d_in[7];
    const float* Wq0 = (const float*)d_in[8];  const float* bq0 = (const float*)d_in[9];
    const float* Wv0 = (const float*)d_in[10]; const float* bv0 = (const float*)d_in[11];
    const float* Wa0 = (const float*)d_in[12]; const float* ba0 = (const float*)d_in[13];
    const float* Wk1 = (const float*)d_in[14]; const float* bk1 = (const float*)d_in[15];
    const float* Wq1 = (const float*)d_in[16]; const float* bq1 = (const float*)d_in[17];
    const float* Wv1 = (const float*)d_in[18]; const float* bv1 = (const float*)d_in[19];
    const float* Wa1 = (const float*)d_in[20]; const float* ba1 = (const float*)d_in[21];
    const float* rel_att = (const float*)d_in[22];
    const float* rel_msg = (const float*)d_in[23];
    const float* rel_pri = (const float*)d_in[24];
    const float* skipv   = (const float*)d_in[25];
    float* out = (float*)d_out;

    char* p = (char*)d_ws;
    auto alloc = [&](size_t bytes) -> char* {
        char* r = p;
        p += (bytes + 255) & ~(size_t)255;
        return r;
    };
    ushort_t* hp_pad = (ushort_t*)alloc((size_t)N_PAD * DIM * 2);
    ushort_t* ha_pad = (ushort_t*)alloc((size_t)N_PAD * DIM * 2);
    ushort_t* qbuf  = (ushort_t*)alloc((size_t)N_PAD * DIM * 2);
    ushort_t* kAbuf = (ushort_t*)alloc((size_t)N_PAD * DIM * 2);
    ushort_t* vMbuf = (ushort_t*)alloc((size_t)N_PAD * DIM * 2);
    ushort_t* tbuf  = (ushort_t*)alloc((size_t)N_PAD * DIM * 2);
    ushort_t* WfkT0 = (ushort_t*)alloc(DIM * DIM * 2);
    ushort_t* WfvT0 = (ushort_t*)alloc(DIM * DIM * 2);
    ushort_t* WfkT1 = (ushort_t*)alloc(DIM * DIM * 2);
    ushort_t* WfvT1 = (ushort_t*)alloc(DIM * DIM * 2);
    ushort_t* WqT0  = (ushort_t*)alloc(DIM * DIM * 2);
    ushort_t* WqT1  = (ushort_t*)alloc(DIM * DIM * 2);
    ushort_t* WaT0  = (ushort_t*)alloc(DIM * DIM * 2);
    ushort_t* WaT1  = (ushort_t*)alloc(DIM * DIM * 2);
    float* bfk0 = (float*)alloc(DIM * 4);
    float* bfv0 = (float*)alloc(DIM * 4);
    float* bfk1 = (float*)alloc(DIM * 4);
    float* bfv1 = (float*)alloc(DIM * 4);
    int* cnt = (int*)alloc((size_t)2 * N_NODES * 4);  // cnt + fill adjacent
    int* fill = cnt + N_NODES;
    int* row_ptr = (int*)alloc((size_t)(N_NODES + 1) * 4);
    int* colarr = (int*)alloc((size_t)N_EDGES * 4);

    // prep
    pad_copy2<<<dim3((N_PAD * DIM / 4 + 255) / 256, 2), 256, 0, stream>>>(h_paper, h_author, hp_pad, ha_pad);
    fuse_weights<<<1024, 256, 0, stream>>>(Wk1, bk1, rel_att,         WfkT0, bfk0);
    fuse_weights<<<1024, 256, 0, stream>>>(Wv1, bv1, rel_msg,         WfvT0, bfv0);
    fuse_weights<<<1024, 256, 0, stream>>>(Wk0, bk0, rel_att + 32768, WfkT1, bfk1);
    fuse_weights<<<1024, 256, 0, stream>>>(Wv0, bv0, rel_msg + 32768, WfvT1, bfv1);
    transpose4<<<dim3(256, 4), 256, 0, stream>>>(Wq0, Wq1, Wa0, Wa1, WqT0, WqT1, WaT0, WaT1);

    for (int rel = 0; rel < 2; ++rel) {
        const int* srcE = rel ? src1 : src0;
        const int* dstE = rel ? dst1 : dst0;
        const ushort_t* hsrc_pad = rel ? hp_pad : ha_pad;  // k/v side
        const ushort_t* hdst_pad = rel ? ha_pad : hp_pad;  // q side
        const float* hdst_res = rel ? h_author : h_paper;  // residual (f32, exact)
        const ushort_t* WqT = rel ? WqT1 : WqT0;
        const float* bqf = rel ? bq1 : bq0;
        const ushort_t* WfkT = rel ? WfkT1 : WfkT0;
        const float* bfk = rel ? bfk1 : bfk0;
        const ushort_t* WfvT = rel ? WfvT1 : WfvT0;
        const float* bfv = rel ? bfv1 : bfv0;
        const ushort_t* WaT = rel ? WaT1 : WaT0;
        const float* baf = rel ? ba1 : ba0;

        hipMemsetAsync(cnt, 0, (size_t)2 * N_NODES * 4, stream);
        hist_kernel<<<(N_EDGES + 255) / 256, 256, 0, stream>>>(dstE, cnt);
        scan_excl<<<1, 1024, 0, stream>>>(cnt, row_ptr);
        scatter_kernel<<<(N_EDGES + 255) / 256, 256, 0, stream>>>(srcE, dstE, row_ptr, fill, colarr);

        gemm512<2><<<940, 256, 0, stream>>>(hdst_pad, WqT, bqf, nullptr, qbuf, nullptr, nullptr, 0);
        gemm512<2><<<940, 256, 0, stream>>>(hsrc_pad, WfkT, bfk, nullptr, kAbuf, nullptr, nullptr, 0);
        gemm512<2><<<940, 256, 0, stream>>>(hsrc_pad, WfvT, bfv, nullptr, vMbuf, nullptr, nullptr, 0);

        node_attn<<<N_PAD * 8 / 4, 256, 0, stream>>>(qbuf, kAbuf, vMbuf, row_ptr, colarr,
                                                     rel_pri + rel * 8, tbuf);

        gemm512<1><<<940, 256, 0, stream>>>(tbuf, WaT, baf,
                                            out + (size_t)rel * N_NODES * DIM, nullptr,
                                            hdst_res, skipv, rel);
    }
}

// Round 3
// 695.381 us; speedup vs baseline: 1.4242x; 1.4242x over previous
//
#include <hip/hip_runtime.h>
#include <hip/hip_bf16.h>
#include <stdint.h>

#define N_NODES 30000
#define N_PAD   30080   // 235 * 128
#define N_EDGES 100000
#define DIM     512
#define QKV_LD  1536    // packed [q | kA | vM] row stride

typedef unsigned short ushort_t;
typedef __attribute__((ext_vector_type(8))) short short8;
typedef __attribute__((ext_vector_type(8))) unsigned short ushortx8;
typedef __attribute__((ext_vector_type(4))) float floatx4;

__device__ __forceinline__ float b2f(ushort_t b) { return __uint_as_float(((unsigned)b) << 16); }
__device__ __forceinline__ ushort_t f2b(float f) {
    unsigned u = __float_as_uint(f);
    u += 0x7FFFu + ((u >> 16) & 1u);   // round-nearest-even
    return (ushort_t)(u >> 16);
}

// ---------------- pad/convert h (f32) into padded bf16 buffers ----------------
__global__ __launch_bounds__(256) void pad_copy2(const float* __restrict__ h0,
                                                 const float* __restrict__ h1,
                                                 ushort_t* __restrict__ d0,
                                                 ushort_t* __restrict__ d1) {
    const int total = N_PAD * DIM / 4;
    const int valid = N_NODES * DIM / 4;
    int idx = blockIdx.x * 256 + threadIdx.x;
    if (idx >= total) return;
    const float* s = blockIdx.y ? h1 : h0;
    ushort_t* d = blockIdx.y ? d1 : d0;
    float4 v = make_float4(0.f, 0.f, 0.f, 0.f);
    if (idx < valid) v = ((const float4*)s)[idx];
    ushort_t o[4] = {f2b(v.x), f2b(v.y), f2b(v.z), f2b(v.w)};
    ((uint2*)d)[idx] = *(const uint2*)o;
}

// ---- fold per-head relation matrix into weight, write into concatenated B^T ----
// out[(off+n)*512 + i] = sum_c W[i][h*64+c] * A[h][c][d]   (n = h*64+d)
// ybias[off+n]         = sum_c b[h*64+c]   * A[h][c][d]
__global__ __launch_bounds__(256) void fuse_weights4(const float* __restrict__ Wk0, const float* __restrict__ bk0,
                                                     const float* __restrict__ Wv0, const float* __restrict__ bv0,
                                                     const float* __restrict__ Wk1, const float* __restrict__ bk1,
                                                     const float* __restrict__ Wv1, const float* __restrict__ bv1,
                                                     const float* __restrict__ rel_att, const float* __restrict__ rel_msg,
                                                     ushort_t* __restrict__ cat_p, ushort_t* __restrict__ cat_a,
                                                     float* __restrict__ bias_p, float* __restrict__ bias_a) {
    const float *W, *bvec, *A;
    ushort_t* outw; float* outb;
    switch (blockIdx.y) {  // rel0 folds into author-side cat, rel1 into paper-side
        case 0: W = Wk1; bvec = bk1; A = rel_att;          outw = cat_a + 512 * DIM;  outb = bias_a + 512;  break;
        case 1: W = Wv1; bvec = bv1; A = rel_msg;          outw = cat_a + 1024 * DIM; outb = bias_a + 1024; break;
        case 2: W = Wk0; bvec = bk0; A = rel_att + 32768;  outw = cat_p + 512 * DIM;  outb = bias_p + 512;  break;
        default: W = Wv0; bvec = bv0; A = rel_msg + 32768; outw = cat_p + 1024 * DIM; outb = bias_p + 1024; break;
    }
    int idx = blockIdx.x * 256 + threadIdx.x;  // 512*512
    int n = idx & 511;
    int i = idx >> 9;
    int h = n >> 6, d = n & 63;
    const float* wrow = W + i * DIM + h * 64;
    const float* acol = A + h * 4096 + d;
    float s = 0.f;
#pragma unroll 8
    for (int c = 0; c < 64; ++c) s += wrow[c] * acol[c * 64];
    outw[n * DIM + i] = f2b(s);
    if (i == 0) {
        const float* bh = bvec + h * 64;
        float sb = 0.f;
        for (int c = 0; c < 64; ++c) sb += bh[c] * acol[c * 64];
        outb[n] = sb;
    }
}

// ---- 4x 512x512 transpose f32 -> bf16: Wq0->cat_p[0:512), Wq1->cat_a[0:512), Wa0/Wa1 -> WaT ----
__global__ __launch_bounds__(256) void transpose4(const float* w0, const float* w1,
                                                  const float* w2, const float* w3,
                                                  ushort_t* o0, ushort_t* o1,
                                                  ushort_t* o2, ushort_t* o3) {
    const float* W; ushort_t* O;
    switch (blockIdx.y) {
        case 0: W = w0; O = o0; break;
        case 1: W = w1; O = o1; break;
        case 2: W = w2; O = o2; break;
        default: W = w3; O = o3; break;
    }
    __shared__ float tile[32][33];
    int bx = blockIdx.x & 15, by = blockIdx.x >> 4;
    int tx = threadIdx.x & 31, ty = threadIdx.x >> 5;  // 32x8
#pragma unroll
    for (int r = 0; r < 32; r += 8) tile[ty + r][tx] = W[(by * 32 + ty + r) * DIM + bx * 32 + tx];
    __syncthreads();
#pragma unroll
    for (int r = 0; r < 32; r += 8) O[(bx * 32 + ty + r) * DIM + by * 32 + tx] = f2b(tile[tx][ty + r]);
}

__global__ __launch_bounds__(256) void copy_biases(const float* bq0, const float* bq1,
                                                   float* bias_p, float* bias_a) {
    int i = blockIdx.x * 256 + threadIdx.x;  // 512
    bias_p[i] = bq0[i];
    bias_a[i] = bq1[i];
}

// ---------------- CSR build (both relations in one pass) ----------------
__global__ __launch_bounds__(256) void hist2(const int* __restrict__ dst0, const int* __restrict__ dst1,
                                             int* __restrict__ cnt) {
    int e = blockIdx.x * 256 + threadIdx.x;
    if (e >= 2 * N_EDGES) return;
    int rel = e >= N_EDGES;
    int d = (rel ? dst1 : dst0)[e - rel * N_EDGES];
    atomicAdd(&cnt[rel * N_NODES + d], 1);
}

__global__ __launch_bounds__(1024) void scan2(const int* __restrict__ cnt, int* __restrict__ row_ptr) {
    int rel = blockIdx.x;
    const int* c = cnt + rel * N_NODES;
    int* rp = row_ptr + rel * (N_NODES + 1);
    __shared__ int sums[1024];
    int tid = threadIdx.x;
    int base = tid * 32;
    int loc[32];
    int s = 0;
#pragma unroll
    for (int i = 0; i < 32; ++i) {
        int idx = base + i;
        int v = (idx < N_NODES) ? c[idx] : 0;
        s += v;
        loc[i] = s;
    }
    sums[tid] = s;
    __syncthreads();
    for (int off = 1; off < 1024; off <<= 1) {
        int add = (tid >= off) ? sums[tid - off] : 0;
        __syncthreads();
        sums[tid] += add;
        __syncthreads();
    }
    int pre = (tid > 0) ? sums[tid - 1] : 0;
    if (tid == 0) rp[0] = 0;
#pragma unroll
    for (int i = 0; i < 32; ++i) {
        int idx = base + i;
        if (idx < N_NODES) rp[idx + 1] = pre + loc[i];
    }
}

__global__ __launch_bounds__(256) void scatter2(const int* __restrict__ src0, const int* __restrict__ dst0,
                                                const int* __restrict__ src1, const int* __restrict__ dst1,
                                                const int* __restrict__ row_ptr,
                                                int* __restrict__ fill,
                                                int* __restrict__ colarr) {
    int e = blockIdx.x * 256 + threadIdx.x;
    if (e >= 2 * N_EDGES) return;
    int rel = e >= N_EDGES;
    int ei = e - rel * N_EDGES;
    int s = (rel ? src1 : src0)[ei];
    int d = (rel ? dst1 : dst0)[ei];
    int pos = atomicAdd(&fill[rel * N_NODES + d], 1);
    colarr[rel * N_EDGES + row_ptr[rel * (N_NODES + 1) + d] + pos] = s;
}

// ---------------- MFMA GEMM core (m97-style, 128x128 tile, BK=32) ----------------
typedef const __attribute__((address_space(1))) unsigned int gu32;
typedef __attribute__((address_space(3))) unsigned int lu32;
__device__ __forceinline__ void gload_lds16(const void* g, void* l) {
    __builtin_amdgcn_global_load_lds((gu32*)g, (lu32*)l, 16, 0, 0);
}

// projection: C[M,1536] = A[M,512] @ BT[1536,512]^T + bias, bf16 out, ldc=1536, both sides via z
__global__ __launch_bounds__(256) void gemm_proj(const ushort_t* __restrict__ Ap, const ushort_t* __restrict__ Aa,
                                                 const ushort_t* __restrict__ Bp, const ushort_t* __restrict__ Ba,
                                                 const float* __restrict__ bias_p, const float* __restrict__ bias_a,
                                                 ushort_t* __restrict__ Cp, ushort_t* __restrict__ Ca) {
    int rel = blockIdx.z;
    const ushort_t* A = rel ? Aa : Ap;
    const ushort_t* BT = rel ? Ba : Bp;
    const float* bias = rel ? bias_a : bias_p;
    ushort_t* C = rel ? Ca : Cp;

    __shared__ alignas(16) ushort_t As[128 * 32];
    __shared__ alignas(16) ushort_t Bs[128 * 32];
    int n0 = blockIdx.x * 128, m0 = blockIdx.y * 128;
    int tid = threadIdx.x;
    int w = tid >> 6, l = tid & 63;
    int wr = w >> 1, wc = w & 1;
    int fr = l & 15, fq = l >> 4;
    floatx4 acc[4][4] = {};
    const ushort_t* aF = &As[(wr * 64 + fr) * 32 + fq * 8];
    const ushort_t* bF = &Bs[(wc * 64 + fr) * 32 + fq * 8];
    int row0 = tid >> 2, c0 = (tid & 3) * 8;
    int row1 = (tid + 256) >> 2;
    int lb0 = (w * 64) * 16;
    int lb1 = (256 + w * 64) * 16;

#pragma unroll 1
    for (int kt = 0; kt < 16; ++kt) {
        int k0 = kt * 32;
        if (kt) __syncthreads();
        gload_lds16(A + (size_t)(m0 + row0) * DIM + k0 + c0, (char*)As + lb0);
        gload_lds16(BT + (size_t)(n0 + row0) * DIM + k0 + c0, (char*)Bs + lb0);
        gload_lds16(A + (size_t)(m0 + row1) * DIM + k0 + c0, (char*)As + lb1);
        gload_lds16(BT + (size_t)(n0 + row1) * DIM + k0 + c0, (char*)Bs + lb1);
        __syncthreads();
        short8 af[4], bf[4];
#pragma unroll
        for (int i = 0; i < 4; ++i) af[i] = *(const short8*)(aF + i * 16 * 32);
#pragma unroll
        for (int j = 0; j < 4; ++j) bf[j] = *(const short8*)(bF + j * 16 * 32);
#pragma unroll
        for (int i = 0; i < 4; ++i)
#pragma unroll
            for (int j = 0; j < 4; ++j)
                acc[i][j] = __builtin_amdgcn_mfma_f32_16x16x32_bf16(af[i], bf[j], acc[i][j], 0, 0, 0);
    }
#pragma unroll
    for (int i = 0; i < 4; ++i)
#pragma unroll
        for (int j = 0; j < 4; ++j) {
            int col = n0 + wc * 64 + j * 16 + fr;
            float bc = bias[col];
#pragma unroll
            for (int r = 0; r < 4; ++r) {
                int grow = m0 + wr * 64 + i * 16 + fq * 4 + r;
                C[(size_t)grow * QKV_LD + col] = f2b(acc[i][j][r] + bc);
            }
        }
}

// out: C[M,512] = T[M,512](lda=1536) @ WaT^T + ba, sigmoid-skip blend vs f32 residual
__global__ __launch_bounds__(256) void gemm_out(const ushort_t* __restrict__ Tp, const ushort_t* __restrict__ Ta,
                                                const ushort_t* __restrict__ Wp, const ushort_t* __restrict__ Wa,
                                                const float* __restrict__ ba0, const float* __restrict__ ba1,
                                                const float* __restrict__ hp, const float* __restrict__ ha,
                                                const float* __restrict__ skipv, float* __restrict__ out) {
    int rel = blockIdx.z;
    const ushort_t* A = rel ? Ta : Tp;
    const ushort_t* BT = rel ? Wa : Wp;
    const float* bias = rel ? ba1 : ba0;
    const float* Hres = rel ? ha : hp;
    float* C = out + (size_t)rel * N_NODES * DIM;

    __shared__ alignas(16) ushort_t As[128 * 32];
    __shared__ alignas(16) ushort_t Bs[128 * 32];
    int n0 = blockIdx.x * 128, m0 = blockIdx.y * 128;
    int tid = threadIdx.x;
    int w = tid >> 6, l = tid & 63;
    int wr = w >> 1, wc = w & 1;
    int fr = l & 15, fq = l >> 4;
    floatx4 acc[4][4] = {};
    const ushort_t* aF = &As[(wr * 64 + fr) * 32 + fq * 8];
    const ushort_t* bF = &Bs[(wc * 64 + fr) * 32 + fq * 8];
    int row0 = tid >> 2, c0 = (tid & 3) * 8;
    int row1 = (tid + 256) >> 2;
    int lb0 = (w * 64) * 16;
    int lb1 = (256 + w * 64) * 16;

#pragma unroll 1
    for (int kt = 0; kt < 16; ++kt) {
        int k0 = kt * 32;
        if (kt) __syncthreads();
        gload_lds16(A + (size_t)(m0 + row0) * QKV_LD + k0 + c0, (char*)As + lb0);
        gload_lds16(BT + (size_t)(n0 + row0) * DIM + k0 + c0, (char*)Bs + lb0);
        gload_lds16(A + (size_t)(m0 + row1) * QKV_LD + k0 + c0, (char*)As + lb1);
        gload_lds16(BT + (size_t)(n0 + row1) * DIM + k0 + c0, (char*)Bs + lb1);
        __syncthreads();
        short8 af[4], bf[4];
#pragma unroll
        for (int i = 0; i < 4; ++i) af[i] = *(const short8*)(aF + i * 16 * 32);
#pragma unroll
        for (int j = 0; j < 4; ++j) bf[j] = *(const short8*)(bF + j * 16 * 32);
#pragma unroll
        for (int i = 0; i < 4; ++i)
#pragma unroll
            for (int j = 0; j < 4; ++j)
                acc[i][j] = __builtin_amdgcn_mfma_f32_16x16x32_bf16(af[i], bf[j], acc[i][j], 0, 0, 0);
    }
    float sk = skipv[rel];
    float alpha = 1.f / (1.f + __expf(-sk));
    float onem = 1.f - alpha;
#pragma unroll
    for (int i = 0; i < 4; ++i)
#pragma unroll
        for (int j = 0; j < 4; ++j) {
            int col = n0 + wc * 64 + j * 16 + fr;
            float bc = bias[col];
#pragma unroll
            for (int r = 0; r < 4; ++r) {
                int grow = m0 + wr * 64 + i * 16 + fq * 4 + r;
                if (grow < N_NODES) {
                    float v = acc[i][j][r] + bc;
                    C[(size_t)grow * DIM + col] = v * alpha + Hres[(size_t)grow * DIM + col] * onem;
                }
            }
        }
}

// ------- per-node online-softmax aggregation: one wave = one node, all 8 heads -------
// lane l owns dims [8l, 8l+8); head h = l>>3. Writes t into the q-columns of qkv_dst.
__global__ __launch_bounds__(256) void node_attn(const ushort_t* __restrict__ qkv_p,
                                                 ushort_t* __restrict__ qkv_p_mut,
                                                 const ushort_t* __restrict__ qkv_a,
                                                 ushort_t* __restrict__ qkv_a_mut,
                                                 const int* __restrict__ row_ptr,
                                                 const int* __restrict__ colarr,
                                                 const float* __restrict__ rel_pri) {
    int rel = blockIdx.y;
    const ushort_t* qkv_dst = rel ? qkv_a : qkv_p;
    ushort_t* t_out = rel ? qkv_a_mut : qkv_p_mut;
    const ushort_t* qkv_src = rel ? qkv_p : qkv_a;
    const int* rp = row_ptr + rel * (N_NODES + 1);
    const int* col = colarr + rel * N_EDGES;
    const float* pri = rel_pri + rel * 8;

    int w = threadIdx.x >> 6, l = threadIdx.x & 63;
    int n = blockIdx.x * 4 + w;  // < N_PAD
    float prih = pri[l >> 3] * 0.125f;  // pri[h] / sqrt(64)

    size_t qoff = (size_t)n * QKV_LD + l * 8;
    ushortx8 qr = *(const ushortx8*)(qkv_dst + qoff);
    float qd[8];
#pragma unroll
    for (int i = 0; i < 8; ++i) qd[i] = b2f(qr[i]);

    int lo = 0, hi = 0;
    if (n < N_NODES) { lo = rp[n]; hi = rp[n + 1]; }

    float m = -3.0e38f, s = 0.f;
    float acc[8] = {};
    int j = lo;
    ushortx8 kr, vr;
    if (j < hi) {
        int sn = col[j];
        const ushort_t* kb = qkv_src + (size_t)sn * QKV_LD + 512 + l * 8;
        kr = *(const ushortx8*)kb;
        vr = *(const ushortx8*)(kb + 512);
    }
    while (j < hi) {
        ushortx8 kc = kr, vc = vr;
        ++j;
        if (j < hi) {  // one-edge lookahead
            int sn = col[j];
            const ushort_t* kb = qkv_src + (size_t)sn * QKV_LD + 512 + l * 8;
            kr = *(const ushortx8*)kb;
            vr = *(const ushortx8*)(kb + 512);
        }
        float dot = 0.f;
#pragma unroll
        for (int i = 0; i < 8; ++i) dot += qd[i] * b2f(kc[i]);
        dot += __shfl_xor(dot, 1);
        dot += __shfl_xor(dot, 2);
        dot += __shfl_xor(dot, 4);   // full head-dot, replicated across 8-lane group
        float att = dot * prih;
        float mn = fmaxf(m, att);
        float e0 = __expf(m - mn);
        float e1 = __expf(att - mn);
        s = s * e0 + e1;
#pragma unroll
        for (int i = 0; i < 8; ++i) acc[i] = acc[i] * e0 + e1 * b2f(vc[i]);
        m = mn;
    }
    float inv = (hi > lo) ? 1.f / s : 0.f;
    ushortx8 o;
#pragma unroll
    for (int i = 0; i < 8; ++i) o[i] = f2b(acc[i] * inv);
    *(ushortx8*)(t_out + qoff) = o;  // overwrite q columns (disjoint from kA/vM reads)
}

// ---------------- host launch ----------------
extern "C" void kernel_launch(void* const* d_in, const int* in_sizes, int n_in,
                              void* d_out, int out_size, void* d_ws, size_t ws_size,
                              hipStream_t stream) {
    (void)in_sizes; (void)n_in; (void)out_size; (void)ws_size;
    const float* h_paper  = (const float*)d_in[0];
    const float* h_author = (const float*)d_in[1];
    const int* src0 = (const int*)d_in[2];
    const int* dst0 = (const int*)d_in[3];
    const int* src1 = (const int*)d_in[4];
    const int* dst1 = (const int*)d_in[5];
    const float* Wk0 = (const float*)d_in[6];  const float* bk0 = (const float*)d_in[7];
    const float* Wq0 = (const float*)d_in[8];  const float* bq0 = (const float*)d_in[9];
    const float* Wv0 = (const float*)d_in[10]; const float* bv0 = (const float*)d_in[11];
    const float* Wa0 = (const float*)d_in[12]; const float* ba0 = (const float*)d_in[13];
    const float* Wk1 = (const float*)d_in[14]; const float* bk1 = (const float*)d_in[15];
    const float* Wq1 = (const float*)d_in[16]; const float* bq1 = (const float*)d_in[17];
    const float* Wv1 = (const float*)d_in[18]; const float* bv1 = (const float*)d_in[19];
    const float* Wa1 = (const float*)d_in[20]; const float* ba1 = (const float*)d_in[21];
    const float* rel_att = (const float*)d_in[22];
    const float* rel_msg = (const float*)d_in[23];
    const float* rel_pri = (const float*)d_in[24];
    const float* skipv   = (const float*)d_in[25];
    float* out = (float*)d_out;

    char* p = (char*)d_ws;
    auto alloc = [&](size_t bytes) -> char* {
        char* r = p;
        p += (bytes + 255) & ~(size_t)255;
        return r;
    };
    ushort_t* hp_pad = (ushort_t*)alloc((size_t)N_PAD * DIM * 2);
    ushort_t* ha_pad = (ushort_t*)alloc((size_t)N_PAD * DIM * 2);
    ushort_t* qkv_p = (ushort_t*)alloc((size_t)N_PAD * QKV_LD * 2);
    ushort_t* qkv_a = (ushort_t*)alloc((size_t)N_PAD * QKV_LD * 2);
    ushort_t* cat_p = (ushort_t*)alloc((size_t)QKV_LD * DIM * 2);
    ushort_t* cat_a = (ushort_t*)alloc((size_t)QKV_LD * DIM * 2);
    ushort_t* WaT0 = (ushort_t*)alloc(DIM * DIM * 2);
    ushort_t* WaT1 = (ushort_t*)alloc(DIM * DIM * 2);
    float* bias_p = (float*)alloc(QKV_LD * 4);
    float* bias_a = (float*)alloc(QKV_LD * 4);
    int* cnt = (int*)alloc((size_t)4 * N_NODES * 4);  // cnt[2N] then fill[2N]
    int* fill = cnt + 2 * N_NODES;
    int* row_ptr = (int*)alloc((size_t)2 * (N_NODES + 1) * 4);
    int* colarr = (int*)alloc((size_t)2 * N_EDGES * 4);

    // prep
    pad_copy2<<<dim3((N_PAD * DIM / 4 + 255) / 256, 2), 256, 0, stream>>>(h_paper, h_author, hp_pad, ha_pad);
    fuse_weights4<<<dim3(1024, 4), 256, 0, stream>>>(Wk0, bk0, Wv0, bv0, Wk1, bk1, Wv1, bv1,
                                                     rel_att, rel_msg, cat_p, cat_a, bias_p, bias_a);
    transpose4<<<dim3(256, 4), 256, 0, stream>>>(Wq0, Wq1, Wa0, Wa1, cat_p, cat_a, WaT0, WaT1);
    copy_biases<<<2, 256, 0, stream>>>(bq0, bq1, bias_p, bias_a);

    // CSR (both relations)
    hipMemsetAsync(cnt, 0, (size_t)4 * N_NODES * 4, stream);
    hist2<<<(2 * N_EDGES + 255) / 256, 256, 0, stream>>>(dst0, dst1, cnt);
    scan2<<<2, 1024, 0, stream>>>(cnt, row_ptr);
    scatter2<<<(2 * N_EDGES + 255) / 256, 256, 0, stream>>>(src0, dst0, src1, dst1, row_ptr, fill, colarr);

    // projections: qkv_p = hp @ [Wq0 | Wk0*A1 | Wv0*M1], qkv_a = ha @ [Wq1 | Wk1*A0 | Wv1*M0]
    gemm_proj<<<dim3(12, 235, 2), 256, 0, stream>>>(hp_pad, ha_pad, cat_p, cat_a, bias_p, bias_a, qkv_p, qkv_a);

    // attention, both relations; t written into q columns of the dst-side qkv
    node_attn<<<dim3(N_PAD / 4, 2), 256, 0, stream>>>(qkv_p, qkv_p, qkv_a, qkv_a, row_ptr, colarr, rel_pri);

    // output GEMMs with sigmoid-skip blend
    gemm_out<<<dim3(4, 235, 2), 256, 0, stream>>>(qkv_p, qkv_a, WaT0, WaT1, ba0, ba1,
                                                  h_paper, h_author, skipv, out);
}